// Round 13
// baseline (348.100 us; speedup 1.0000x reference)
//
#include <hip/hip_runtime.h>

#define TT 512
#define BIGS 1.4426950408889634e10f   // BIG(1e10) * log2(e), scaled domain
#define LOG2E 1.4426950408889634f
#define M2L  (-2.0f * 1.4426950408889634f)
#define LN2F 0.69314718055994531f
#define P_SS 16                       // ticks per superstep (barrier period)
#define G_LAG 80                      // band lag in ticks (>= P_SS + 63 + 1)
#define N_SS 51                       // band3 last tick 574 at s=50

typedef _Float16 h2 __attribute__((ext_vector_type(2)));

__device__ __forceinline__ unsigned pk(float a, float b) {
    h2 v; v.x = (_Float16)a; v.y = (_Float16)b;
    return __builtin_bit_cast(unsigned, v);
}

#if __has_builtin(__builtin_amdgcn_fdot2)
#define FDOT2(a, b, c) __builtin_amdgcn_fdot2(__builtin_bit_cast(h2, (a)), \
                                              __builtin_bit_cast(h2, (b)), (c), false)
#else
__device__ __forceinline__ float fdot2_sw(unsigned a, unsigned b, float c) {
    h2 ha = __builtin_bit_cast(h2, a), hb = __builtin_bit_cast(h2, b);
    return c + (float)ha.x * (float)hb.x + (float)ha.y * (float)hb.y;
}
#define FDOT2(a, b, c) fdot2_sw((a), (b), (c))
#endif

// permuted Z index, pure bitops (valid for any int j; wraps out-of-range j
// onto some valid row -- garbage rows only feed masked-out ticks)
#define ZROW(jv) (((((jv) & 1)) << 8) | ((((jv) >> 1)) & 255))

// ---------------------------------------------------------------------------
// Banded column-marching fused SoftDTW, (K,sm) split form -- r12 tick with
// TWO samples per block: 512 thr = 8 waves = 2 samples x 4 bands ->
// 2 waves/SIMD so independent samples' chain/LDS stalls interleave (r12 ran
// 1 wave/SIMD; 45% VALU-busy per CU = 55% dead issue slots). The Z LDS
// image is sample-independent and shared; only the seam rings duplicate.
// Seam (K,S) interleaved as float2 -> single b64 read/write per tick.
// __launch_bounds__(512,2) caps VGPR at 256 (kernel ~48; no r4-style spill).
// Schedule/numerics identical to r12 (verified): lag 80, barrier per 16
// ticks, exact pow-2 renorm per 8 ticks, borders exact via (BIGS,1).
// ---------------------------------------------------------------------------
__global__ __launch_bounds__(512, 2) void k_fused(const float* __restrict__ X,
                                                  const float* __restrict__ Z,
                                                  const float* __restrict__ w,
                                                  float* __restrict__ out) {
    const int tt   = threadIdx.x;
    const int t    = tt & 63;            // lane
    const int band = (tt >> 6) & 3;      // row band 0..3
    const int samp = tt >> 8;            // sample slot 0..1
    const int n    = blockIdx.x * 2 + samp;

    __shared__ uint4  ZA[2][512];        // Z rows fp16-packed, permuted idx (shared)
    __shared__ float  Zs2p[512];         // LOG2E*|z|^2 at permuted idx (shared)
    __shared__ float2 seam[2][4][64];    // (K,S) rings; band0 = const border

    // ---- stage Z into LDS: thread tt handles row tt ----
    {
        const int r = tt;
        const float4* zp = (const float4*)(Z + (size_t)r * 16);
        const float4 a0 = zp[0], a1 = zp[1], a2 = zp[2], a3 = zp[3];
        float sv = 0.0f;
        sv = fmaf(a0.x, a0.x, sv); sv = fmaf(a0.y, a0.y, sv);
        sv = fmaf(a0.z, a0.z, sv); sv = fmaf(a0.w, a0.w, sv);
        sv = fmaf(a1.x, a1.x, sv); sv = fmaf(a1.y, a1.y, sv);
        sv = fmaf(a1.z, a1.z, sv); sv = fmaf(a1.w, a1.w, sv);
        sv = fmaf(a2.x, a2.x, sv); sv = fmaf(a2.y, a2.y, sv);
        sv = fmaf(a2.z, a2.z, sv); sv = fmaf(a2.w, a2.w, sv);
        sv = fmaf(a3.x, a3.x, sv); sv = fmaf(a3.y, a3.y, sv);
        sv = fmaf(a3.z, a3.z, sv); sv = fmaf(a3.w, a3.w, sv);
        const int idx = ((r & 1) << 8) | (r >> 1);
        ZA[0][idx] = make_uint4(pk(a0.x, a0.y), pk(a0.z, a0.w),
                                pk(a1.x, a1.y), pk(a1.z, a1.w));
        ZA[1][idx] = make_uint4(pk(a2.x, a2.y), pk(a2.z, a2.w),
                                pk(a3.x, a3.y), pk(a3.z, a3.w));
        Zs2p[idx] = LOG2E * sv;
    }
    // seam rings -> (BIGS, 1): matrix border; band-0 rings never written
    (&seam[0][0][0])[tt] = make_float2(BIGS, 1.0f);

    // ---- X rows for this lane (rows i0, i0+1) -> registers ----
    const int i0 = 128 * band + 2 * t;
    unsigned Xu[2][8];
    float    xs2[2];
    const float* xp = X + ((size_t)n * TT + i0) * 16;
#pragma unroll
    for (int q = 0; q < 2; ++q) {
        const float4* xr = (const float4*)(xp + q * 16);
        const float4 a0 = xr[0], a1 = xr[1], a2 = xr[2], a3 = xr[3];
        float sv = 0.0f;
        sv = fmaf(a0.x, a0.x, sv); sv = fmaf(a0.y, a0.y, sv);
        sv = fmaf(a0.z, a0.z, sv); sv = fmaf(a0.w, a0.w, sv);
        sv = fmaf(a1.x, a1.x, sv); sv = fmaf(a1.y, a1.y, sv);
        sv = fmaf(a1.z, a1.z, sv); sv = fmaf(a1.w, a1.w, sv);
        sv = fmaf(a2.x, a2.x, sv); sv = fmaf(a2.y, a2.y, sv);
        sv = fmaf(a2.z, a2.z, sv); sv = fmaf(a2.w, a2.w, sv);
        sv = fmaf(a3.x, a3.x, sv); sv = fmaf(a3.y, a3.y, sv);
        sv = fmaf(a3.z, a3.z, sv); sv = fmaf(a3.w, a3.w, sv);
        xs2[q] = LOG2E * sv;
        Xu[q][0] = pk(a0.x, a0.y); Xu[q][1] = pk(a0.z, a0.w);
        Xu[q][2] = pk(a1.x, a1.y); Xu[q][3] = pk(a1.z, a1.w);
        Xu[q][4] = pk(a2.x, a2.y); Xu[q][5] = pk(a2.z, a2.w);
        Xu[q][6] = pk(a3.x, a3.y); Xu[q][7] = pk(a3.z, a3.w);
    }
    const float wgt = w[n];
    const float2* rSeam = &seam[samp][band][0];
    __syncthreads();

    float RpK[2], RpS[2], poK, poS, bnK, bnS;
    float2 smv;
    uint4 Zb[2][2];
    float zsb[2];
    RpK[0] = RpK[1] = BIGS; RpS[0] = RpS[1] = 1.0f;
    poK = BIGS; poS = 1.0f; smv = make_float2(BIGS, 1.0f);
    bnK = BIGS; bnS = 1.0f;
    zsb[0] = zsb[1] = 0.0f;
    Zb[0][0] = Zb[0][1] = Zb[1][0] = Zb[1][1] = make_uint4(0, 0, 0, 0);

#define TICK(par, tl)                                                          \
    {                                                                          \
        const float unK = (t == 0) ? smv.x : bnK;                              \
        const float unS = (t == 0) ? smv.y : bnS;                              \
        smv = rSeam[((tl) + 1) & 63];        /* seam for next tick (b64) */    \
        const uint4 z0 = Zb[par][0], z1 = Zb[par][1];                          \
        const float zz = zsb[par];                                             \
        {   /* refill this slot with the row for tick tl+2 */                  \
            const int xn = ZROW((tl) + 2 - t);                                 \
            Zb[par][0] = ZA[0][xn];                                            \
            Zb[par][1] = ZA[1][xn];                                            \
            zsb[par] = Zs2p[xn];                                               \
        }                                                                      \
        float a0 = 0.0f, a1 = 0.0f;                                            \
        a0 = FDOT2(z0.x, Xu[0][0], a0); a0 = FDOT2(z0.y, Xu[0][1], a0);        \
        a0 = FDOT2(z0.z, Xu[0][2], a0); a0 = FDOT2(z0.w, Xu[0][3], a0);        \
        a0 = FDOT2(z1.x, Xu[0][4], a0); a0 = FDOT2(z1.y, Xu[0][5], a0);        \
        a0 = FDOT2(z1.z, Xu[0][6], a0); a0 = FDOT2(z1.w, Xu[0][7], a0);        \
        a1 = FDOT2(z0.x, Xu[1][0], a1); a1 = FDOT2(z0.y, Xu[1][1], a1);        \
        a1 = FDOT2(z0.z, Xu[1][2], a1); a1 = FDOT2(z0.w, Xu[1][3], a1);        \
        a1 = FDOT2(z1.x, Xu[1][4], a1); a1 = FDOT2(z1.y, Xu[1][5], a1);        \
        a1 = FDOT2(z1.z, Xu[1][6], a1); a1 = FDOT2(z1.w, Xu[1][7], a1);        \
        const float dd0 = fmaf(M2L, a0, xs2[0] + zz);                          \
        const float dd1 = fmaf(M2L, a1, xs2[1] + zz);                          \
        /* (K,sm) softmin, unconditional (all operands finite) */              \
        const float l0K = RpK[0], l0S = RpS[0];                                \
        const float m0 = fminf(fminf(unK, l0K), poK);                          \
        const float s0 = exp2f(m0 - unK) * unS                                 \
                       + exp2f(m0 - l0K) * l0S                                 \
                       + exp2f(m0 - poK) * poS;                                \
        const float K0 = dd0 + m0;                                             \
        const float l1K = RpK[1], l1S = RpS[1];                                \
        const float m1 = fminf(fminf(K0, l1K), l0K);                           \
        const float s1 = exp2f(m1 - K0) * s0                                   \
                       + exp2f(m1 - l1K) * l1S                                 \
                       + exp2f(m1 - l0K) * l0S;                                \
        const float K1 = dd1 + m1;                                             \
        const int j = (tl) - t;                                                \
        const bool ok = (j >= 0) && (j < 512);                                 \
        RpK[0] = ok ? K0 : RpK[0];  RpS[0] = ok ? s0 : RpS[0];                 \
        RpK[1] = ok ? K1 : RpK[1];  RpS[1] = ok ? s1 : RpS[1];                 \
        if (ok && band < 3 && t == 63) {                                       \
            seam[samp][band + 1][j & 63] = make_float2(RpK[1], RpS[1]);        \
        }                                                                      \
        poK = unK; poS = unS;                                                  \
        bnK = __shfl_up(RpK[1], 1);          /* boundary for tick tl+1 */      \
        bnS = __shfl_up(RpS[1], 1);                                            \
    }

#define RENORM                                                                 \
    {                                                                          \
        _Pragma("unroll")                                                      \
        for (int q = 0; q < 2; ++q) {                                          \
            const int e = (int)(__float_as_uint(RpS[q]) >> 23) - 127;          \
            RpS[q] = __uint_as_float(__float_as_uint(RpS[q])                   \
                                     - ((unsigned)e << 23));                   \
            RpK[q] -= (float)e;                                                \
        }                                                                      \
    }

#pragma unroll 1
    for (int s = 0; s < N_SS; ++s) {
        const int tb = P_SS * s - G_LAG * band;
        if (tb >= 0 && tb <= 574) {
            if (tb == 0) {
                // activation: state + boundary + Z buffers for ticks 0,1
                RpK[0] = RpK[1] = BIGS; RpS[0] = RpS[1] = 1.0f;
                poK = (band == 0 && t == 0) ? 0.0f : BIGS; poS = 1.0f; // corner
                bnK = BIGS; bnS = 1.0f;
                smv = rSeam[0];
                const int x0 = ZROW(0 - t);
                const int x1 = ZROW(1 - t);
                Zb[0][0] = ZA[0][x0]; Zb[0][1] = ZA[1][x0]; zsb[0] = Zs2p[x0];
                Zb[1][0] = ZA[0][x1]; Zb[1][1] = ZA[1][x1]; zsb[1] = Zs2p[x1];
            }
            TICK(0, tb + 0)  TICK(1, tb + 1)  TICK(0, tb + 2)  TICK(1, tb + 3)
            TICK(0, tb + 4)  TICK(1, tb + 5)  TICK(0, tb + 6)  TICK(1, tb + 7)
            RENORM
            TICK(0, tb + 8)  TICK(1, tb + 9)  TICK(0, tb + 10) TICK(1, tb + 11)
            TICK(0, tb + 12) TICK(1, tb + 13) TICK(0, tb + 14) TICK(1, tb + 15)
            RENORM
        }
        __syncthreads();
    }
#undef TICK
#undef RENORM

    // band 3, lane 63, row 511 at tick 574 -> R(511,511) = K - log2(sm)
    if (band == 3 && t == 63) {
        atomicAdd(out, wgt * (RpK[1] - log2f(RpS[1])) * LN2F);
    }
}

__global__ void k_zero(float* out) {
    if (threadIdx.x == 0) out[0] = 0.0f;
}

extern "C" void kernel_launch(void* const* d_in, const int* in_sizes, int n_in,
                              void* d_out, int out_size, void* d_ws, size_t ws_size,
                              hipStream_t stream) {
    const float* X = (const float*)d_in[0];   // (64, 512, 16) f32
    const float* w = (const float*)d_in[1];   // (64,) f32
    const float* Z = (const float*)d_in[2];   // (512, 16) f32
    float* out = (float*)d_out;               // scalar f32

    hipLaunchKernelGGL(k_zero, dim3(1), dim3(64), 0, stream, out);
    hipLaunchKernelGGL(k_fused, dim3(32), dim3(512), 0, stream, X, Z, w, out);
}